// Round 1
// baseline (1450.888 us; speedup 1.0000x reference)
//
#include <hip/hip_runtime.h>
#include <stdint.h>

#define C_CH 192
#define H_IN 128
#define W_IN 128
#define H_DS 64
#define W_DS 64
#define L_P  4096      // 64*64 patch positions
#define K_P  1728      // 192*9
#define N_BG 3072      // 16*192

typedef __bf16 bf16x8 __attribute__((ext_vector_type(8)));
typedef float  f32x4  __attribute__((ext_vector_type(4)));

typedef void __attribute__((address_space(1))) as1_void;
typedef void __attribute__((address_space(3))) as3_void;

__device__ __forceinline__ void gload_lds16(const void* g, void* l) {
  __builtin_amdgcn_global_load_lds((as1_void*)g, (as3_void*)l, 16, 0, 0);
}

__device__ __forceinline__ uint16_t f2bf(float f) {
  uint32_t u = __float_as_uint(f);
  u = (u + 0x7FFFu + ((u >> 16) & 1u)) >> 16;
  return (uint16_t)u;
}

// ---------------- bilinear downsample 128->64, align_corners=True ----------
__global__ __launch_bounds__(256) void k_downsample(const float* __restrict__ in,
                                                    float* __restrict__ out) {
  int idx = blockIdx.x * 256 + threadIdx.x;            // over 768*4096
  int ox = idx & 63, oy = (idx >> 6) & 63, bc = idx >> 12;
  const float sc = 127.0f / 63.0f;
  float ysf = oy * sc, xsf = ox * sc;
  int y0 = (int)ysf, x0 = (int)xsf;
  int y1 = min(y0 + 1, 127), x1 = min(x0 + 1, 127);
  float wy = ysf - (float)y0, wx = xsf - (float)x0;
  const float* p = in + (size_t)bc * (H_IN * W_IN);
  float a = p[y0 * W_IN + x0], b = p[y0 * W_IN + x1];
  float c = p[y1 * W_IN + x0], d = p[y1 * W_IN + x1];
  float top = a * (1.0f - wx) + b * wx;
  float bot = c * (1.0f - wx) + d * wx;
  out[idx] = top * (1.0f - wy) + bot * wy;
}

// ---------------- build PT[l][k] bf16 (k = c*9 + ki*3 + kj), per sample -----
__global__ void k_pbuild(const float* __restrict__ fgds, uint16_t* __restrict__ PT) {
  int x = threadIdx.x;                 // 64
  int y = blockIdx.x;                  // 64
  int c = blockIdx.y * 4 + threadIdx.y; // 192
  const float* src = fgds + (size_t)c * (H_DS * W_DS);
  int l = y * 64 + x;
  uint16_t* dst = PT + (size_t)l * K_P + c * 9;
  #pragma unroll
  for (int ki = 0; ki < 3; ++ki)
    #pragma unroll
    for (int kj = 0; kj < 3; ++kj) {
      int yy = y + ki - 1, xx = x + kj - 1;
      float v = (yy >= 0 && yy < 64 && xx >= 0 && xx < 64) ? src[yy * 64 + xx] : 0.0f;
      dst[ki * 3 + kj] = f2bf(v);
    }
}

// ---------------- scale[l] = 10 / max(||patch_l||, 1e-4), fp32, per sample --
__global__ void k_scale(const float* __restrict__ fgds, float* __restrict__ scale) {
  int l = blockIdx.x;
  int y = l >> 6, x = l & 63;
  int c = threadIdx.x;                 // 192 threads = 3 waves
  const float* src = fgds + (size_t)c * (H_DS * W_DS);
  float ss = 0.0f;
  #pragma unroll
  for (int ki = 0; ki < 3; ++ki)
    #pragma unroll
    for (int kj = 0; kj < 3; ++kj) {
      int yy = y + ki - 1, xx = x + kj - 1;
      float v = (yy >= 0 && yy < 64 && xx >= 0 && xx < 64) ? src[yy * 64 + xx] : 0.0f;
      ss += v * v;
    }
  for (int off = 32; off; off >>= 1) ss += __shfl_xor(ss, off);
  __shared__ float red[3];
  if ((c & 63) == 0) red[c >> 6] = ss;
  __syncthreads();
  if (c == 0) {
    float s = red[0] + red[1] + red[2];
    scale[l] = 10.0f / fmaxf(sqrtf(s), 1e-4f);
  }
}

// ---------------- build BgT[(ki*4+kj)*192 + c][l] bf16, per sample ----------
__global__ void k_bgbuild(const float* __restrict__ bg, uint16_t* __restrict__ BgT) {
  int x = threadIdx.x;                 // 64
  int y = blockIdx.x;                  // 64
  int c = blockIdx.y * 4 + threadIdx.y; // 192
  const float* src = bg + (size_t)c * (H_IN * W_IN);
  int l = y * 64 + x;
  #pragma unroll
  for (int ki = 0; ki < 4; ++ki)
    #pragma unroll
    for (int kj = 0; kj < 4; ++kj) {
      int yy = 2 * y + ki - 1, xx = 2 * x + kj - 1;
      float v = (yy >= 0 && yy < H_IN && xx >= 0 && xx < W_IN) ? src[yy * W_IN + xx] : 0.0f;
      BgT[((size_t)((ki * 4 + kj) * C_CH + c)) * L_P + l] = f2bf(v);
    }
}

// ---------------- GEMM: C[m][n] = sum_k A[m*K+k]*B[n*K+k]  (bf16 in, f32 out)
// m97-style: 128x128 tile, BK=64, 4 waves 2x2, global_load_lds width 16.
// CT: write C transposed as C[n*M+m] (float4 per lane, fully-covered sectors).
template <bool CT>
__global__ __launch_bounds__(256) void k_gemm(const uint16_t* __restrict__ A,
                                              const uint16_t* __restrict__ B,
                                              float* __restrict__ Cmat,
                                              int M, int N, int K) {
  __shared__ alignas(16) uint16_t As[128 * 64];
  __shared__ alignas(16) uint16_t Bs[128 * 64];
  const int tid = threadIdx.x;
  const int wave = tid >> 6;
  const int lane = tid & 63;
  const int tileM = blockIdx.y * 128;
  const int tileN = blockIdx.x * 128;

  const int srow = wave * 8 + (lane >> 3);     // + j*32
  const int schunk = (lane & 7) * 8;
  const uint16_t* gA = A + (size_t)(tileM + srow) * K + schunk;
  const uint16_t* gB = B + (size_t)(tileN + srow) * K + schunk;
  uint16_t* lA = As + wave * 512;              // + j*2048
  uint16_t* lB = Bs + wave * 512;

  f32x4 acc[4][4] = {};

  const int wm = (wave >> 1) * 64;
  const int wn = (wave & 1) * 64;
  const int fr = lane & 15;
  const int fk = (lane >> 4) * 8;

  for (int k0 = 0; k0 < K; k0 += 64) {
    #pragma unroll
    for (int j = 0; j < 4; ++j) {
      gload_lds16(gA + (size_t)j * 32 * K + k0, lA + j * 2048);
      gload_lds16(gB + (size_t)j * 32 * K + k0, lB + j * 2048);
    }
    __syncthreads();
    #pragma unroll
    for (int kk = 0; kk < 64; kk += 32) {
      bf16x8 av[4], bv[4];
      #pragma unroll
      for (int mi = 0; mi < 4; ++mi)
        av[mi] = *(const bf16x8*)(As + (wm + mi * 16 + fr) * 64 + kk + fk);
      #pragma unroll
      for (int ni = 0; ni < 4; ++ni)
        bv[ni] = *(const bf16x8*)(Bs + (wn + ni * 16 + fr) * 64 + kk + fk);
      #pragma unroll
      for (int mi = 0; mi < 4; ++mi)
        #pragma unroll
        for (int ni = 0; ni < 4; ++ni)
          acc[mi][ni] = __builtin_amdgcn_mfma_f32_16x16x32_bf16(av[mi], bv[ni],
                                                                acc[mi][ni], 0, 0, 0);
    }
    __syncthreads();
  }

  const int r0 = (lane >> 4) * 4;
  #pragma unroll
  for (int mi = 0; mi < 4; ++mi)
    #pragma unroll
    for (int ni = 0; ni < 4; ++ni) {
      const int m = tileM + wm + mi * 16 + r0;
      const int n = tileN + wn + ni * 16 + fr;
      if (CT) {
        *(f32x4*)(Cmat + (size_t)n * M + m) = acc[mi][ni];
      } else {
        #pragma unroll
        for (int r = 0; r < 4; ++r)
          Cmat[(size_t)(m + r) * N + n] = acc[mi][ni][r];
      }
    }
}

// ---------------- row softmax: attn[p][l] = clip(softmax_l(S[p][l]*scale[l]),1e-8)
__global__ __launch_bounds__(256) void k_softmax(const float* __restrict__ S,
                                                 const float* __restrict__ scale,
                                                 uint16_t* __restrict__ attn) {
  int p = blockIdx.x, t = threadIdx.x;
  const float4* row = (const float4*)(S + (size_t)p * L_P);
  const float4* sc4 = (const float4*)scale;
  float v[16];
  float mx = -3.4e38f;
  #pragma unroll
  for (int i = 0; i < 4; ++i) {
    float4 g = row[i * 256 + t];
    float4 s = sc4[i * 256 + t];
    v[i * 4 + 0] = g.x * s.x;
    v[i * 4 + 1] = g.y * s.y;
    v[i * 4 + 2] = g.z * s.z;
    v[i * 4 + 3] = g.w * s.w;
    mx = fmaxf(mx, fmaxf(fmaxf(v[i * 4], v[i * 4 + 1]), fmaxf(v[i * 4 + 2], v[i * 4 + 3])));
  }
  __shared__ float red[8];
  for (int off = 32; off; off >>= 1) mx = fmaxf(mx, __shfl_xor(mx, off));
  if ((t & 63) == 0) red[t >> 6] = mx;
  __syncthreads();
  mx = fmaxf(fmaxf(red[0], red[1]), fmaxf(red[2], red[3]));
  float sum = 0.0f;
  #pragma unroll
  for (int i = 0; i < 16; ++i) {
    v[i] = __expf(v[i] - mx);
    sum += v[i];
  }
  for (int off = 32; off; off >>= 1) sum += __shfl_xor(sum, off);
  if ((t & 63) == 0) red[4 + (t >> 6)] = sum;
  __syncthreads();
  sum = red[4] + red[5] + red[6] + red[7];
  float inv = 1.0f / sum;
  uint2* orow = (uint2*)(attn + (size_t)p * L_P);
  #pragma unroll
  for (int i = 0; i < 4; ++i) {
    uint32_t b0 = f2bf(fmaxf(v[i * 4 + 0] * inv, 1e-8f));
    uint32_t b1 = f2bf(fmaxf(v[i * 4 + 1] * inv, 1e-8f));
    uint32_t b2 = f2bf(fmaxf(v[i * 4 + 2] * inv, 1e-8f));
    uint32_t b3 = f2bf(fmaxf(v[i * 4 + 3] * inv, 1e-8f));
    uint2 o;
    o.x = b0 | (b1 << 16);
    o.y = b2 | (b3 << 16);
    orow[i * 256 + t] = o;
  }
}

// ---------------- gather O2T[(ki*4+kj)*192+c][p] -> out[c][Y][X], /4 --------
__global__ __launch_bounds__(256) void k_gather(const float* __restrict__ O2T,
                                                float* __restrict__ out) {
  int t = blockIdx.x * 256 + threadIdx.x;   // over 192*128*128
  int X = t & 127, Y = (t >> 7) & 127, c = t >> 14;
  int ty = Y >> 1, tx = X >> 1;
  int ya, kia, yb, kib, xa, kja, xb, kjb;
  if (Y & 1) { ya = ty;     kia = 2; yb = ty + 1; kib = 0; }
  else       { ya = ty - 1; kia = 3; yb = ty;     kib = 1; }
  if (X & 1) { xa = tx;     kja = 2; xb = tx + 1; kjb = 0; }
  else       { xa = tx - 1; kja = 3; xb = tx;     kjb = 1; }
  bool yav = (ya >= 0 && ya < 64), ybv = (yb >= 0 && yb < 64);
  bool xav = (xa >= 0 && xa < 64), xbv = (xb >= 0 && xb < 64);
  float s = 0.0f;
  if (yav && xav) s += O2T[((size_t)((kia * 4 + kja) * C_CH + c)) * L_P + ya * 64 + xa];
  if (yav && xbv) s += O2T[((size_t)((kia * 4 + kjb) * C_CH + c)) * L_P + ya * 64 + xb];
  if (ybv && xav) s += O2T[((size_t)((kib * 4 + kja) * C_CH + c)) * L_P + yb * 64 + xa];
  if (ybv && xbv) s += O2T[((size_t)((kib * 4 + kjb) * C_CH + c)) * L_P + yb * 64 + xb];
  out[t] = 0.25f * s;
}

extern "C" void kernel_launch(void* const* d_in, const int* in_sizes, int n_in,
                              void* d_out, int out_size, void* d_ws, size_t ws_size,
                              hipStream_t stream) {
  const float* bg = (const float*)d_in[0];
  const float* fg = (const float*)d_in[1];
  float* out = (float*)d_out;
  char* ws = (char*)d_ws;

  // workspace layout (bytes)
  float*    fgds  = (float*)(ws + 0);            // 4*192*64*64*4  = 12,582,912
  uint16_t* PT    = (uint16_t*)(ws + 12582912);  // 4096*1728*2    = 14,155,776
  float*    scale = (float*)(ws + 26738688);     // 4096*4         = 16,384
  uint16_t* BgT   = (uint16_t*)(ws + 26755072);  // 3072*4096*2    = 25,165,824
  float*    Sbuf  = (float*)(ws + 51920896);     // 4096*4096*4    = 67,108,864 (also O2T)
  uint16_t* attn  = (uint16_t*)(ws + 119029760); // 4096*4096*2    = 33,554,432
  (void)ws_size; (void)in_sizes; (void)n_in; (void)out_size;

  k_downsample<<<12288, 256, 0, stream>>>(fg, fgds);

  for (int b = 0; b < 4; ++b) {
    const float* bg_b = bg + (size_t)b * C_CH * H_IN * W_IN;
    const float* fg_b = fgds + (size_t)b * C_CH * H_DS * W_DS;
    float* out_b = out + (size_t)b * C_CH * H_IN * W_IN;

    k_pbuild<<<dim3(64, 48), dim3(64, 4), 0, stream>>>(fg_b, PT);
    k_scale<<<4096, 192, 0, stream>>>(fg_b, scale);
    k_bgbuild<<<dim3(64, 48), dim3(64, 4), 0, stream>>>(bg_b, BgT);

    // GEMM1: S[p][l] = <P_p, P_l>, M=N=4096, K=1728
    k_gemm<false><<<dim3(32, 32), 256, 0, stream>>>(PT, PT, Sbuf, 4096, 4096, 1728);

    k_softmax<<<4096, 256, 0, stream>>>(Sbuf, scale, attn);

    // GEMM2: O2T[n][p] = sum_l attn[p][l]*BgT[n][l], M=4096, N=3072, K=4096
    k_gemm<true><<<dim3(24, 32), 256, 0, stream>>>(attn, BgT, Sbuf, 4096, 3072, 4096);

    k_gather<<<12288, 256, 0, stream>>>(Sbuf, out_b);
  }
}

// Round 2
// 1258.353 us; speedup vs baseline: 1.1530x; 1.1530x over previous
//
#include <hip/hip_runtime.h>
#include <stdint.h>

#define C_CH 192
#define H_IN 128
#define W_IN 128
#define H_DS 64
#define W_DS 64
#define L_P  4096      // 64*64 patch positions
#define K_P  1728      // 192*9
#define N_BG 3072      // 16*192

typedef __bf16 bf16x8 __attribute__((ext_vector_type(8)));
typedef float  f32x4  __attribute__((ext_vector_type(4)));

typedef void __attribute__((address_space(1))) as1_void;
typedef void __attribute__((address_space(3))) as3_void;

__device__ __forceinline__ void gload_lds16(const void* g, void* l) {
  __builtin_amdgcn_global_load_lds((as1_void*)g, (as3_void*)l, 16, 0, 0);
}

__device__ __forceinline__ uint16_t f2bf(float f) {
  uint32_t u = __float_as_uint(f);
  u = (u + 0x7FFFu + ((u >> 16) & 1u)) >> 16;
  return (uint16_t)u;
}

// ---------------- bilinear downsample 128->64, align_corners=True ----------
__global__ __launch_bounds__(256) void k_downsample(const float* __restrict__ in,
                                                    float* __restrict__ out) {
  int idx = blockIdx.x * 256 + threadIdx.x;            // over 768*4096
  int ox = idx & 63, oy = (idx >> 6) & 63, bc = idx >> 12;
  const float sc = 127.0f / 63.0f;
  float ysf = oy * sc, xsf = ox * sc;
  int y0 = (int)ysf, x0 = (int)xsf;
  int y1 = min(y0 + 1, 127), x1 = min(x0 + 1, 127);
  float wy = ysf - (float)y0, wx = xsf - (float)x0;
  const float* p = in + (size_t)bc * (H_IN * W_IN);
  float a = p[y0 * W_IN + x0], b = p[y0 * W_IN + x1];
  float c = p[y1 * W_IN + x0], d = p[y1 * W_IN + x1];
  float top = a * (1.0f - wx) + b * wx;
  float bot = c * (1.0f - wx) + d * wx;
  out[idx] = top * (1.0f - wy) + bot * wy;
}

// ---------------- build PT[l][k] bf16 (k = c*9 + ki*3 + kj), per sample -----
__global__ void k_pbuild(const float* __restrict__ fgds, uint16_t* __restrict__ PT) {
  int x = threadIdx.x;                 // 64
  int y = blockIdx.x;                  // 64
  int c = blockIdx.y * 4 + threadIdx.y; // 192
  const float* src = fgds + (size_t)c * (H_DS * W_DS);
  int l = y * 64 + x;
  uint16_t* dst = PT + (size_t)l * K_P + c * 9;
  #pragma unroll
  for (int ki = 0; ki < 3; ++ki)
    #pragma unroll
    for (int kj = 0; kj < 3; ++kj) {
      int yy = y + ki - 1, xx = x + kj - 1;
      float v = (yy >= 0 && yy < 64 && xx >= 0 && xx < 64) ? src[yy * 64 + xx] : 0.0f;
      dst[ki * 3 + kj] = f2bf(v);
    }
}

// ---------------- scale[l] = 10 / max(||patch_l||, 1e-4), fp32, per sample --
__global__ void k_scale(const float* __restrict__ fgds, float* __restrict__ scale) {
  int l = blockIdx.x;
  int y = l >> 6, x = l & 63;
  int c = threadIdx.x;                 // 192 threads = 3 waves
  const float* src = fgds + (size_t)c * (H_DS * W_DS);
  float ss = 0.0f;
  #pragma unroll
  for (int ki = 0; ki < 3; ++ki)
    #pragma unroll
    for (int kj = 0; kj < 3; ++kj) {
      int yy = y + ki - 1, xx = x + kj - 1;
      float v = (yy >= 0 && yy < 64 && xx >= 0 && xx < 64) ? src[yy * 64 + xx] : 0.0f;
      ss += v * v;
    }
  for (int off = 32; off; off >>= 1) ss += __shfl_xor(ss, off);
  __shared__ float red[3];
  if ((c & 63) == 0) red[c >> 6] = ss;
  __syncthreads();
  if (c == 0) {
    float s = red[0] + red[1] + red[2];
    scale[l] = 10.0f / fmaxf(sqrtf(s), 1e-4f);
  }
}

// ---------------- build BgT[(ki*4+kj)*192 + c][l] bf16, per sample ----------
__global__ void k_bgbuild(const float* __restrict__ bg, uint16_t* __restrict__ BgT) {
  int x = threadIdx.x;                 // 64
  int y = blockIdx.x;                  // 64
  int c = blockIdx.y * 4 + threadIdx.y; // 192
  const float* src = bg + (size_t)c * (H_IN * W_IN);
  int l = y * 64 + x;
  #pragma unroll
  for (int ki = 0; ki < 4; ++ki)
    #pragma unroll
    for (int kj = 0; kj < 4; ++kj) {
      int yy = 2 * y + ki - 1, xx = 2 * x + kj - 1;
      float v = (yy >= 0 && yy < H_IN && xx >= 0 && xx < W_IN) ? src[yy * W_IN + xx] : 0.0f;
      BgT[((size_t)((ki * 4 + kj) * C_CH + c)) * L_P + l] = f2bf(v);
    }
}

// ---------------- GEMM: C[m][n] = sum_k A[m*K+k]*B[n*K+k]  (bf16 in, f32 out)
// m97-style: 128x128 tile, BK=64, 4 waves 2x2, global_load_lds width 16.
// T2 LDS swizzle (rule #21, both-sides): LDS dest stays linear; the global
// SOURCE chunk is permuted per lane (chunk = (lane&7) ^ (lane>>3)), and the
// ds_read column applies the same XOR ((row&7)<<3 in elements). This turns
// the 16-way bank conflict of the 128B-stride row reads into 2-way (free).
// CT: write C transposed as C[n*M+m] (float4 per lane, fully-covered sectors).
template <bool CT>
__global__ __launch_bounds__(256) void k_gemm(const uint16_t* __restrict__ A,
                                              const uint16_t* __restrict__ B,
                                              float* __restrict__ Cmat,
                                              int M, int N, int K) {
  __shared__ alignas(16) uint16_t As[128 * 64];
  __shared__ alignas(16) uint16_t Bs[128 * 64];
  const int tid = threadIdx.x;
  const int wave = tid >> 6;
  const int lane = tid & 63;
  const int tileM = blockIdx.y * 128;
  const int tileN = blockIdx.x * 128;

  const int srow = wave * 8 + (lane >> 3);                 // + j*32
  const int schunk = ((lane & 7) ^ (lane >> 3)) * 8;       // pre-swizzled source
  const uint16_t* gA = A + (size_t)(tileM + srow) * K + schunk;
  const uint16_t* gB = B + (size_t)(tileN + srow) * K + schunk;
  uint16_t* lA = As + wave * 512;              // + j*2048
  uint16_t* lB = Bs + wave * 512;

  f32x4 acc[4][4] = {};

  const int wm = (wave >> 1) * 64;
  const int wn = (wave & 1) * 64;
  const int fr = lane & 15;
  const int fk = (lane >> 4) * 8;
  const int xr = (fr & 7) << 3;                // read-side XOR (elements)

  for (int k0 = 0; k0 < K; k0 += 64) {
    #pragma unroll
    for (int j = 0; j < 4; ++j) {
      gload_lds16(gA + (size_t)j * 32 * K + k0, lA + j * 2048);
      gload_lds16(gB + (size_t)j * 32 * K + k0, lB + j * 2048);
    }
    __syncthreads();
    #pragma unroll
    for (int kk = 0; kk < 64; kk += 32) {
      bf16x8 av[4], bv[4];
      const int col = (kk + fk) ^ xr;
      #pragma unroll
      for (int mi = 0; mi < 4; ++mi)
        av[mi] = *(const bf16x8*)(As + (wm + mi * 16 + fr) * 64 + col);
      #pragma unroll
      for (int ni = 0; ni < 4; ++ni)
        bv[ni] = *(const bf16x8*)(Bs + (wn + ni * 16 + fr) * 64 + col);
      #pragma unroll
      for (int mi = 0; mi < 4; ++mi)
        #pragma unroll
        for (int ni = 0; ni < 4; ++ni)
          acc[mi][ni] = __builtin_amdgcn_mfma_f32_16x16x32_bf16(av[mi], bv[ni],
                                                                acc[mi][ni], 0, 0, 0);
    }
    __syncthreads();
  }

  const int r0 = (lane >> 4) * 4;
  #pragma unroll
  for (int mi = 0; mi < 4; ++mi)
    #pragma unroll
    for (int ni = 0; ni < 4; ++ni) {
      const int m = tileM + wm + mi * 16 + r0;
      const int n = tileN + wn + ni * 16 + fr;
      if (CT) {
        *(f32x4*)(Cmat + (size_t)n * M + m) = acc[mi][ni];
      } else {
        #pragma unroll
        for (int r = 0; r < 4; ++r)
          Cmat[(size_t)(m + r) * N + n] = acc[mi][ni][r];
      }
    }
}

// ---------------- row softmax: attn[p][l] = clip(softmax_l(S[p][l]*scale[l]),1e-8)
__global__ __launch_bounds__(256) void k_softmax(const float* __restrict__ S,
                                                 const float* __restrict__ scale,
                                                 uint16_t* __restrict__ attn) {
  int p = blockIdx.x, t = threadIdx.x;
  const float4* row = (const float4*)(S + (size_t)p * L_P);
  const float4* sc4 = (const float4*)scale;
  float v[16];
  float mx = -3.4e38f;
  #pragma unroll
  for (int i = 0; i < 4; ++i) {
    float4 g = row[i * 256 + t];
    float4 s = sc4[i * 256 + t];
    v[i * 4 + 0] = g.x * s.x;
    v[i * 4 + 1] = g.y * s.y;
    v[i * 4 + 2] = g.z * s.z;
    v[i * 4 + 3] = g.w * s.w;
    mx = fmaxf(mx, fmaxf(fmaxf(v[i * 4], v[i * 4 + 1]), fmaxf(v[i * 4 + 2], v[i * 4 + 3])));
  }
  __shared__ float red[8];
  for (int off = 32; off; off >>= 1) mx = fmaxf(mx, __shfl_xor(mx, off));
  if ((t & 63) == 0) red[t >> 6] = mx;
  __syncthreads();
  mx = fmaxf(fmaxf(red[0], red[1]), fmaxf(red[2], red[3]));
  float sum = 0.0f;
  #pragma unroll
  for (int i = 0; i < 16; ++i) {
    v[i] = __expf(v[i] - mx);
    sum += v[i];
  }
  for (int off = 32; off; off >>= 1) sum += __shfl_xor(sum, off);
  if ((t & 63) == 0) red[4 + (t >> 6)] = sum;
  __syncthreads();
  sum = red[4] + red[5] + red[6] + red[7];
  float inv = 1.0f / sum;
  uint2* orow = (uint2*)(attn + (size_t)p * L_P);
  #pragma unroll
  for (int i = 0; i < 4; ++i) {
    uint32_t b0 = f2bf(fmaxf(v[i * 4 + 0] * inv, 1e-8f));
    uint32_t b1 = f2bf(fmaxf(v[i * 4 + 1] * inv, 1e-8f));
    uint32_t b2 = f2bf(fmaxf(v[i * 4 + 2] * inv, 1e-8f));
    uint32_t b3 = f2bf(fmaxf(v[i * 4 + 3] * inv, 1e-8f));
    uint2 o;
    o.x = b0 | (b1 << 16);
    o.y = b2 | (b3 << 16);
    orow[i * 256 + t] = o;
  }
}

// ---------------- gather O2T[(ki*4+kj)*192+c][p] -> out[c][Y][X], /4 --------
__global__ __launch_bounds__(256) void k_gather(const float* __restrict__ O2T,
                                                float* __restrict__ out) {
  int t = blockIdx.x * 256 + threadIdx.x;   // over 192*128*128
  int X = t & 127, Y = (t >> 7) & 127, c = t >> 14;
  int ty = Y >> 1, tx = X >> 1;
  int ya, kia, yb, kib, xa, kja, xb, kjb;
  if (Y & 1) { ya = ty;     kia = 2; yb = ty + 1; kib = 0; }
  else       { ya = ty - 1; kia = 3; yb = ty;     kib = 1; }
  if (X & 1) { xa = tx;     kja = 2; xb = tx + 1; kjb = 0; }
  else       { xa = tx - 1; kja = 3; xb = tx;     kjb = 1; }
  bool yav = (ya >= 0 && ya < 64), ybv = (yb >= 0 && yb < 64);
  bool xav = (xa >= 0 && xa < 64), xbv = (xb >= 0 && xb < 64);
  float s = 0.0f;
  if (yav && xav) s += O2T[((size_t)((kia * 4 + kja) * C_CH + c)) * L_P + ya * 64 + xa];
  if (yav && xbv) s += O2T[((size_t)((kia * 4 + kjb) * C_CH + c)) * L_P + ya * 64 + xb];
  if (ybv && xav) s += O2T[((size_t)((kib * 4 + kja) * C_CH + c)) * L_P + yb * 64 + xa];
  if (ybv && xbv) s += O2T[((size_t)((kib * 4 + kjb) * C_CH + c)) * L_P + yb * 64 + xb];
  out[t] = 0.25f * s;
}

extern "C" void kernel_launch(void* const* d_in, const int* in_sizes, int n_in,
                              void* d_out, int out_size, void* d_ws, size_t ws_size,
                              hipStream_t stream) {
  const float* bg = (const float*)d_in[0];
  const float* fg = (const float*)d_in[1];
  float* out = (float*)d_out;
  char* ws = (char*)d_ws;

  // workspace layout (bytes)
  float*    fgds  = (float*)(ws + 0);            // 4*192*64*64*4  = 12,582,912
  uint16_t* PT    = (uint16_t*)(ws + 12582912);  // 4096*1728*2    = 14,155,776
  float*    scale = (float*)(ws + 26738688);     // 4096*4         = 16,384
  uint16_t* BgT   = (uint16_t*)(ws + 26755072);  // 3072*4096*2    = 25,165,824
  float*    Sbuf  = (float*)(ws + 51920896);     // 4096*4096*4    = 67,108,864 (also O2T)
  uint16_t* attn  = (uint16_t*)(ws + 119029760); // 4096*4096*2    = 33,554,432
  (void)ws_size; (void)in_sizes; (void)n_in; (void)out_size;

  k_downsample<<<12288, 256, 0, stream>>>(fg, fgds);

  for (int b = 0; b < 4; ++b) {
    const float* bg_b = bg + (size_t)b * C_CH * H_IN * W_IN;
    const float* fg_b = fgds + (size_t)b * C_CH * H_DS * W_DS;
    float* out_b = out + (size_t)b * C_CH * H_IN * W_IN;

    k_pbuild<<<dim3(64, 48), dim3(64, 4), 0, stream>>>(fg_b, PT);
    k_scale<<<4096, 192, 0, stream>>>(fg_b, scale);
    k_bgbuild<<<dim3(64, 48), dim3(64, 4), 0, stream>>>(bg_b, BgT);

    // GEMM1: S[p][l] = <P_p, P_l>, M=N=4096, K=1728
    k_gemm<false><<<dim3(32, 32), 256, 0, stream>>>(PT, PT, Sbuf, 4096, 4096, 1728);

    k_softmax<<<4096, 256, 0, stream>>>(Sbuf, scale, attn);

    // GEMM2: O2T[n][p] = sum_l attn[p][l]*BgT[n][l], M=4096, N=3072, K=4096
    k_gemm<true><<<dim3(24, 32), 256, 0, stream>>>(attn, BgT, Sbuf, 4096, 3072, 4096);

    k_gather<<<12288, 256, 0, stream>>>(Sbuf, out_b);
  }
}

// Round 3
// 1180.979 us; speedup vs baseline: 1.2285x; 1.0655x over previous
//
#include <hip/hip_runtime.h>
#include <stdint.h>

#define C_CH 192
#define H_IN 128
#define W_IN 128
#define H_DS 64
#define W_DS 64
#define L_P  4096      // 64*64 patch positions
#define K_P  1728      // 192*9
#define N_BG 3072      // 16*192

typedef __bf16 bf16x8 __attribute__((ext_vector_type(8)));
typedef float  f32x4  __attribute__((ext_vector_type(4)));

typedef void __attribute__((address_space(1))) as1_void;
typedef void __attribute__((address_space(3))) as3_void;

__device__ __forceinline__ void gload_lds16(const void* g, void* l) {
  __builtin_amdgcn_global_load_lds((as1_void*)g, (as3_void*)l, 16, 0, 0);
}

__device__ __forceinline__ uint16_t f2bf(float f) {
  uint32_t u = __float_as_uint(f);
  u = (u + 0x7FFFu + ((u >> 16) & 1u)) >> 16;
  return (uint16_t)u;
}

#define BARRIER() do { asm volatile("" ::: "memory"); \
                       __builtin_amdgcn_s_barrier();  \
                       asm volatile("" ::: "memory"); } while (0)

// ---------------- bilinear downsample 128->64, align_corners=True ----------
__global__ __launch_bounds__(256) void k_downsample(const float* __restrict__ in,
                                                    float* __restrict__ out) {
  int idx = blockIdx.x * 256 + threadIdx.x;            // over 768*4096
  int ox = idx & 63, oy = (idx >> 6) & 63, bc = idx >> 12;
  const float sc = 127.0f / 63.0f;
  float ysf = oy * sc, xsf = ox * sc;
  int y0 = (int)ysf, x0 = (int)xsf;
  int y1 = min(y0 + 1, 127), x1 = min(x0 + 1, 127);
  float wy = ysf - (float)y0, wx = xsf - (float)x0;
  const float* p = in + (size_t)bc * (H_IN * W_IN);
  float a = p[y0 * W_IN + x0], b = p[y0 * W_IN + x1];
  float c = p[y1 * W_IN + x0], d = p[y1 * W_IN + x1];
  float top = a * (1.0f - wx) + b * wx;
  float bot = c * (1.0f - wx) + d * wx;
  out[idx] = top * (1.0f - wy) + bot * wy;
}

// ---------------- build PT[l][k] bf16 (k = c*9 + ki*3 + kj), per sample -----
__global__ void k_pbuild(const float* __restrict__ fgds, uint16_t* __restrict__ PT) {
  int x = threadIdx.x;                 // 64
  int y = blockIdx.x;                  // 64
  int c = blockIdx.y * 4 + threadIdx.y; // 192
  const float* src = fgds + (size_t)c * (H_DS * W_DS);
  int l = y * 64 + x;
  uint16_t* dst = PT + (size_t)l * K_P + c * 9;
  #pragma unroll
  for (int ki = 0; ki < 3; ++ki)
    #pragma unroll
    for (int kj = 0; kj < 3; ++kj) {
      int yy = y + ki - 1, xx = x + kj - 1;
      float v = (yy >= 0 && yy < 64 && xx >= 0 && xx < 64) ? src[yy * 64 + xx] : 0.0f;
      dst[ki * 3 + kj] = f2bf(v);
    }
}

// ---------------- scale[l] = 10 / max(||patch_l||, 1e-4), fp32, per sample --
__global__ void k_scale(const float* __restrict__ fgds, float* __restrict__ scale) {
  int l = blockIdx.x;
  int y = l >> 6, x = l & 63;
  int c = threadIdx.x;                 // 192 threads = 3 waves
  const float* src = fgds + (size_t)c * (H_DS * W_DS);
  float ss = 0.0f;
  #pragma unroll
  for (int ki = 0; ki < 3; ++ki)
    #pragma unroll
    for (int kj = 0; kj < 3; ++kj) {
      int yy = y + ki - 1, xx = x + kj - 1;
      float v = (yy >= 0 && yy < 64 && xx >= 0 && xx < 64) ? src[yy * 64 + xx] : 0.0f;
      ss += v * v;
    }
  for (int off = 32; off; off >>= 1) ss += __shfl_xor(ss, off);
  __shared__ float red[3];
  if ((c & 63) == 0) red[c >> 6] = ss;
  __syncthreads();
  if (c == 0) {
    float s = red[0] + red[1] + red[2];
    scale[l] = 10.0f / fmaxf(sqrtf(s), 1e-4f);
  }
}

// ---------------- build BgT[(ki*4+kj)*192 + c][l] bf16, per sample ----------
__global__ void k_bgbuild(const float* __restrict__ bg, uint16_t* __restrict__ BgT) {
  int x = threadIdx.x;                 // 64
  int y = blockIdx.x;                  // 64
  int c = blockIdx.y * 4 + threadIdx.y; // 192
  const float* src = bg + (size_t)c * (H_IN * W_IN);
  int l = y * 64 + x;
  #pragma unroll
  for (int ki = 0; ki < 4; ++ki)
    #pragma unroll
    for (int kj = 0; kj < 4; ++kj) {
      int yy = 2 * y + ki - 1, xx = 2 * x + kj - 1;
      float v = (yy >= 0 && yy < H_IN && xx >= 0 && xx < W_IN) ? src[yy * W_IN + xx] : 0.0f;
      BgT[((size_t)((ki * 4 + kj) * C_CH + c)) * L_P + l] = f2bf(v);
    }
}

// ======================= 256x256 8-phase GEMM (T2+T3+T4+T5) =================
// C^T[n][m] = sum_k A[m*K+k]*B[n*K+k], bf16 in, f32 out, written transposed.
// 8 waves (2M x 4N), per-wave 128x64 out. BK=64, double-buffered 128 KiB LDS.
// A halves: m-lo rows {0-63,128-191}, m-hi rows {64-127,192-255} (per-wave
// m-lo/hi quadrant split). B halves: n-lo cols {0-31,64-95,...}, n-hi compl.
// Phase p of tile t: ph0=(mlo,nlo) stages A-hi(t+1); ph1=(mlo,nhi) stages
// B-hi(t+1); ph2=(mhi,nlo) stages A-lo(t+2); ph3=(mhi,nhi) stages B-lo(t+2).
// Each prefetch target slot's last reader finished a barrier earlier (WAR-
// safe). vmcnt(6) before the closing barrier of ph0 and ph3 (counted, never
// 0 in steady state); tail tiles tighten to vmcnt(2)/vmcnt(0).

#define STAGE_A(BUF, HALF, TT) do {                                            \
  const int rbA0 = ((wave >> 2) * 128) + ((wave & 3) * 8) + (HALF) * 64;       \
  gload_lds16(A + (size_t)(tileM + rbA0      + srow8) * K + (size_t)(TT) * 64 + schunk, \
              SA[BUF] + (rbA0)      * 64);                                     \
  gload_lds16(A + (size_t)(tileM + rbA0 + 32 + srow8) * K + (size_t)(TT) * 64 + schunk, \
              SA[BUF] + (rbA0 + 32) * 64);                                     \
} while (0)

#define STAGE_B(BUF, HALF, TT) do {                                            \
  const int rbB0 = ((wave >> 2) * 64) + ((wave & 3) * 8) + (HALF) * 32;        \
  gload_lds16(B + (size_t)(tileN + rbB0       + srow8) * K + (size_t)(TT) * 64 + schunk, \
              SB[BUF] + (rbB0)       * 64);                                    \
  gload_lds16(B + (size_t)(tileN + rbB0 + 128 + srow8) * K + (size_t)(TT) * 64 + schunk, \
              SB[BUF] + (rbB0 + 128) * 64);                                    \
} while (0)

#define PHASE(MH, NH, STAGE_STMT, TAIL_STMT) do {                              \
  bf16x8 av[4][2], bv[2][2];                                                   \
  const uint16_t* SAc = SA[cur];                                               \
  const uint16_t* SBc = SB[cur];                                               \
  _Pragma("unroll")                                                            \
  for (int m2 = 0; m2 < 4; ++m2) {                                             \
    const int r = (wave >> 2) * 128 + (MH) * 64 + m2 * 16 + fr;                \
    _Pragma("unroll")                                                          \
    for (int ks = 0; ks < 2; ++ks)                                             \
      av[m2][ks] = *(const bf16x8*)(SAc + r * 64 + ((ks * 32 + fk) ^ xr));     \
  }                                                                            \
  _Pragma("unroll")                                                            \
  for (int n2 = 0; n2 < 2; ++n2) {                                             \
    const int r = (wave & 3) * 64 + (NH) * 32 + n2 * 16 + fr;                  \
    _Pragma("unroll")                                                          \
    for (int ks = 0; ks < 2; ++ks)                                             \
      bv[n2][ks] = *(const bf16x8*)(SBc + r * 64 + ((ks * 32 + fk) ^ xr));     \
  }                                                                            \
  STAGE_STMT                                                                   \
  BARRIER();                                                                   \
  __builtin_amdgcn_s_setprio(1);                                               \
  _Pragma("unroll")                                                            \
  for (int m2 = 0; m2 < 4; ++m2)                                               \
    _Pragma("unroll")                                                          \
    for (int n2 = 0; n2 < 2; ++n2)                                             \
      _Pragma("unroll")                                                        \
      for (int ks = 0; ks < 2; ++ks)                                           \
        acc[(MH)*4 + m2][(NH)*2 + n2] = __builtin_amdgcn_mfma_f32_16x16x32_bf16( \
            av[m2][ks], bv[n2][ks], acc[(MH)*4 + m2][(NH)*2 + n2], 0, 0, 0);   \
  __builtin_amdgcn_s_setprio(0);                                               \
  TAIL_STMT                                                                    \
  BARRIER();                                                                   \
} while (0)

__global__ __launch_bounds__(512, 2) void k_gemm256(const uint16_t* __restrict__ A,
                                                    const uint16_t* __restrict__ B,
                                                    float* __restrict__ Cmat,
                                                    int M, int N, int K) {
  __shared__ alignas(16) uint16_t SA[2][256 * 64];
  __shared__ alignas(16) uint16_t SB[2][256 * 64];
  const int tid = threadIdx.x;
  const int wave = tid >> 6, lane = tid & 63;
  const int tileM = blockIdx.y * 256, tileN = blockIdx.x * 256;
  const int srow8 = lane >> 3;
  const int schunk = ((lane & 7) ^ srow8) * 8;   // source-side T2 swizzle
  const int fr = lane & 15, fk = (lane >> 4) * 8;
  const int xr = (fr & 7) << 3;                  // read-side T2 swizzle (elems)
  const int NT = K >> 6;
  (void)N;

  f32x4 acc[8][4] = {};

  // prologue: [Alo0, Blo0, Ahi0, Bhi0, Alo1, Blo1] then counted wait
  STAGE_A(0, 0, 0);
  STAGE_B(0, 0, 0);
  STAGE_A(0, 1, 0);
  STAGE_B(0, 1, 0);
  if (NT > 1) {
    STAGE_A(1, 0, 1);
    STAGE_B(1, 0, 1);
    asm volatile("s_waitcnt vmcnt(6)" ::: "memory");
  } else {
    asm volatile("s_waitcnt vmcnt(2)" ::: "memory");
  }
  BARRIER();

  for (int t = 0; t < NT; ++t) {
    const int cur = t & 1, nxt = cur ^ 1;
    PHASE(0, 0,
          { if (t + 1 < NT) STAGE_A(nxt, 1, t + 1); },
          { if (t == NT - 1) asm volatile("s_waitcnt vmcnt(0)" ::: "memory");
            else             asm volatile("s_waitcnt vmcnt(6)" ::: "memory"); });
    PHASE(0, 1,
          { if (t + 1 < NT) STAGE_B(nxt, 1, t + 1); },
          { });
    PHASE(1, 0,
          { if (t + 2 < NT) STAGE_A(cur, 0, t + 2); },
          { });
    PHASE(1, 1,
          { if (t + 2 < NT) STAGE_B(cur, 0, t + 2); },
          { if (t <= NT - 3)      asm volatile("s_waitcnt vmcnt(6)" ::: "memory");
            else if (t == NT - 2) asm volatile("s_waitcnt vmcnt(2)" ::: "memory"); });
  }

  // epilogue: C^T write, float4 per fragment row-group
  const int r0 = (lane >> 4) * 4;
  #pragma unroll
  for (int ai = 0; ai < 8; ++ai) {
    const int m = tileM + (wave >> 2) * 128 + (ai >> 2) * 64 + (ai & 3) * 16 + r0;
    #pragma unroll
    for (int bi = 0; bi < 4; ++bi) {
      const int n = tileN + (wave & 3) * 64 + (bi >> 1) * 32 + (bi & 1) * 16 + fr;
      *(f32x4*)(Cmat + (size_t)n * M + m) = acc[ai][bi];
    }
  }
}

// ---------------- row softmax: attn[p][l] = clip(softmax_l(S[p][l]*scale[l]),1e-8)
__global__ __launch_bounds__(256) void k_softmax(const float* __restrict__ S,
                                                 const float* __restrict__ scale,
                                                 uint16_t* __restrict__ attn) {
  int p = blockIdx.x, t = threadIdx.x;
  const float4* row = (const float4*)(S + (size_t)p * L_P);
  const float4* sc4 = (const float4*)scale;
  float v[16];
  float mx = -3.4e38f;
  #pragma unroll
  for (int i = 0; i < 4; ++i) {
    float4 g = row[i * 256 + t];
    float4 s = sc4[i * 256 + t];
    v[i * 4 + 0] = g.x * s.x;
    v[i * 4 + 1] = g.y * s.y;
    v[i * 4 + 2] = g.z * s.z;
    v[i * 4 + 3] = g.w * s.w;
    mx = fmaxf(mx, fmaxf(fmaxf(v[i * 4], v[i * 4 + 1]), fmaxf(v[i * 4 + 2], v[i * 4 + 3])));
  }
  __shared__ float red[8];
  for (int off = 32; off; off >>= 1) mx = fmaxf(mx, __shfl_xor(mx, off));
  if ((t & 63) == 0) red[t >> 6] = mx;
  __syncthreads();
  mx = fmaxf(fmaxf(red[0], red[1]), fmaxf(red[2], red[3]));
  float sum = 0.0f;
  #pragma unroll
  for (int i = 0; i < 16; ++i) {
    v[i] = __expf(v[i] - mx);
    sum += v[i];
  }
  for (int off = 32; off; off >>= 1) sum += __shfl_xor(sum, off);
  if ((t & 63) == 0) red[4 + (t >> 6)] = sum;
  __syncthreads();
  sum = red[4] + red[5] + red[6] + red[7];
  float inv = 1.0f / sum;
  uint2* orow = (uint2*)(attn + (size_t)p * L_P);
  #pragma unroll
  for (int i = 0; i < 4; ++i) {
    uint32_t b0 = f2bf(fmaxf(v[i * 4 + 0] * inv, 1e-8f));
    uint32_t b1 = f2bf(fmaxf(v[i * 4 + 1] * inv, 1e-8f));
    uint32_t b2 = f2bf(fmaxf(v[i * 4 + 2] * inv, 1e-8f));
    uint32_t b3 = f2bf(fmaxf(v[i * 4 + 3] * inv, 1e-8f));
    uint2 o;
    o.x = b0 | (b1 << 16);
    o.y = b2 | (b3 << 16);
    orow[i * 256 + t] = o;
  }
}

// ---------------- gather O2T[(ki*4+kj)*192+c][p] -> out[c][Y][X], /4 --------
__global__ __launch_bounds__(256) void k_gather(const float* __restrict__ O2T,
                                                float* __restrict__ out) {
  int t = blockIdx.x * 256 + threadIdx.x;   // over 192*128*128
  int X = t & 127, Y = (t >> 7) & 127, c = t >> 14;
  int ty = Y >> 1, tx = X >> 1;
  int ya, kia, yb, kib, xa, kja, xb, kjb;
  if (Y & 1) { ya = ty;     kia = 2; yb = ty + 1; kib = 0; }
  else       { ya = ty - 1; kia = 3; yb = ty;     kib = 1; }
  if (X & 1) { xa = tx;     kja = 2; xb = tx + 1; kjb = 0; }
  else       { xa = tx - 1; kja = 3; xb = tx;     kjb = 1; }
  bool yav = (ya >= 0 && ya < 64), ybv = (yb >= 0 && yb < 64);
  bool xav = (xa >= 0 && xa < 64), xbv = (xb >= 0 && xb < 64);
  float s = 0.0f;
  if (yav && xav) s += O2T[((size_t)((kia * 4 + kja) * C_CH + c)) * L_P + ya * 64 + xa];
  if (yav && xbv) s += O2T[((size_t)((kia * 4 + kjb) * C_CH + c)) * L_P + ya * 64 + xb];
  if (ybv && xav) s += O2T[((size_t)((kib * 4 + kja) * C_CH + c)) * L_P + yb * 64 + xa];
  if (ybv && xbv) s += O2T[((size_t)((kib * 4 + kjb) * C_CH + c)) * L_P + yb * 64 + xb];
  out[t] = 0.25f * s;
}

extern "C" void kernel_launch(void* const* d_in, const int* in_sizes, int n_in,
                              void* d_out, int out_size, void* d_ws, size_t ws_size,
                              hipStream_t stream) {
  const float* bg = (const float*)d_in[0];
  const float* fg = (const float*)d_in[1];
  float* out = (float*)d_out;
  char* ws = (char*)d_ws;

  // workspace layout (bytes)
  float*    fgds  = (float*)(ws + 0);            // 4*192*64*64*4  = 12,582,912
  uint16_t* PT    = (uint16_t*)(ws + 12582912);  // 4096*1728*2    = 14,155,776
  float*    scale = (float*)(ws + 26738688);     // 4096*4         = 16,384
  uint16_t* BgT   = (uint16_t*)(ws + 26755072);  // 3072*4096*2    = 25,165,824
  float*    Sbuf  = (float*)(ws + 51920896);     // 4096*4096*4    = 67,108,864 (also O2T)
  uint16_t* attn  = (uint16_t*)(ws + 119029760); // 4096*4096*2    = 33,554,432
  (void)ws_size; (void)in_sizes; (void)n_in; (void)out_size;

  k_downsample<<<12288, 256, 0, stream>>>(fg, fgds);

  for (int b = 0; b < 4; ++b) {
    const float* bg_b = bg + (size_t)b * C_CH * H_IN * W_IN;
    const float* fg_b = fgds + (size_t)b * C_CH * H_DS * W_DS;
    float* out_b = out + (size_t)b * C_CH * H_IN * W_IN;

    k_pbuild<<<dim3(64, 48), dim3(64, 4), 0, stream>>>(fg_b, PT);
    k_scale<<<4096, 192, 0, stream>>>(fg_b, scale);
    k_bgbuild<<<dim3(64, 48), dim3(64, 4), 0, stream>>>(bg_b, BgT);

    // GEMM1: S^T == S (Gram, symmetric), M=N=4096, K=1728
    k_gemm256<<<dim3(16, 16), 512, 0, stream>>>(PT, PT, Sbuf, 4096, 4096, 1728);

    k_softmax<<<4096, 256, 0, stream>>>(Sbuf, scale, attn);

    // GEMM2: O2T[n][p] = sum_l attn[p][l]*BgT[n][l], M=4096, N=3072, K=4096
    k_gemm256<<<dim3(12, 16), 512, 0, stream>>>(attn, BgT, Sbuf, 4096, 3072, 4096);

    k_gather<<<12288, 256, 0, stream>>>(Sbuf, out_b);
  }
}

// Round 4
// 1078.216 us; speedup vs baseline: 1.3456x; 1.0953x over previous
//
#include <hip/hip_runtime.h>
#include <stdint.h>

#define C_CH 192
#define H_IN 128
#define W_IN 128
#define H_DS 64
#define W_DS 64
#define L_P  4096      // 64*64 patch positions
#define K_P  1728      // 192*9
#define N_BG 3072      // 16*192

typedef __bf16 bf16x8 __attribute__((ext_vector_type(8)));
typedef float  f32x4  __attribute__((ext_vector_type(4)));

typedef void __attribute__((address_space(1))) as1_void;
typedef void __attribute__((address_space(3))) as3_void;

__device__ __forceinline__ void gload_lds16(const void* g, void* l) {
  __builtin_amdgcn_global_load_lds((as1_void*)g, (as3_void*)l, 16, 0, 0);
}

__device__ __forceinline__ uint16_t f2bf(float f) {
  uint32_t u = __float_as_uint(f);
  u = (u + 0x7FFFu + ((u >> 16) & 1u)) >> 16;
  return (uint16_t)u;
}

#define BARRIER() do { asm volatile("" ::: "memory"); \
                       __builtin_amdgcn_s_barrier();  \
                       asm volatile("" ::: "memory"); } while (0)

// ---------------- bilinear downsample 128->64, align_corners=True ----------
__global__ __launch_bounds__(256) void k_downsample(const float* __restrict__ in,
                                                    float* __restrict__ out) {
  int idx = blockIdx.x * 256 + threadIdx.x;            // over 768*4096
  int ox = idx & 63, oy = (idx >> 6) & 63, bc = idx >> 12;
  const float sc = 127.0f / 63.0f;
  float ysf = oy * sc, xsf = ox * sc;
  int y0 = (int)ysf, x0 = (int)xsf;
  int y1 = min(y0 + 1, 127), x1 = min(x0 + 1, 127);
  float wy = ysf - (float)y0, wx = xsf - (float)x0;
  const float* p = in + (size_t)bc * (H_IN * W_IN);
  float a = p[y0 * W_IN + x0], b = p[y0 * W_IN + x1];
  float c = p[y1 * W_IN + x0], d = p[y1 * W_IN + x1];
  float top = a * (1.0f - wx) + b * wx;
  float bot = c * (1.0f - wx) + d * wx;
  out[idx] = top * (1.0f - wy) + bot * wy;
}

// ---------------- build PT[l][k] bf16 (k = c*9 + ki*3 + kj), per sample -----
__global__ void k_pbuild(const float* __restrict__ fgds, uint16_t* __restrict__ PT) {
  int x = threadIdx.x;                 // 64
  int y = blockIdx.x;                  // 64
  int c = blockIdx.y * 4 + threadIdx.y; // 192
  const float* src = fgds + (size_t)c * (H_DS * W_DS);
  int l = y * 64 + x;
  uint16_t* dst = PT + (size_t)l * K_P + c * 9;
  #pragma unroll
  for (int ki = 0; ki < 3; ++ki)
    #pragma unroll
    for (int kj = 0; kj < 3; ++kj) {
      int yy = y + ki - 1, xx = x + kj - 1;
      float v = (yy >= 0 && yy < 64 && xx >= 0 && xx < 64) ? src[yy * 64 + xx] : 0.0f;
      dst[ki * 3 + kj] = f2bf(v);
    }
}

// ---------------- scale[l] = 10 / max(||patch_l||, 1e-4), fp32, per sample --
__global__ void k_scale(const float* __restrict__ fgds, float* __restrict__ scale) {
  int l = blockIdx.x;
  int y = l >> 6, x = l & 63;
  int c = threadIdx.x;                 // 192 threads = 3 waves
  const float* src = fgds + (size_t)c * (H_DS * W_DS);
  float ss = 0.0f;
  #pragma unroll
  for (int ki = 0; ki < 3; ++ki)
    #pragma unroll
    for (int kj = 0; kj < 3; ++kj) {
      int yy = y + ki - 1, xx = x + kj - 1;
      float v = (yy >= 0 && yy < 64 && xx >= 0 && xx < 64) ? src[yy * 64 + xx] : 0.0f;
      ss += v * v;
    }
  for (int off = 32; off; off >>= 1) ss += __shfl_xor(ss, off);
  __shared__ float red[3];
  if ((c & 63) == 0) red[c >> 6] = ss;
  __syncthreads();
  if (c == 0) {
    float s = red[0] + red[1] + red[2];
    scale[l] = 10.0f / fmaxf(sqrtf(s), 1e-4f);
  }
}

// ---------------- build BgT[(ki*4+kj)*192 + c][l] bf16, per sample ----------
__global__ void k_bgbuild(const float* __restrict__ bg, uint16_t* __restrict__ BgT) {
  int x = threadIdx.x;                 // 64
  int y = blockIdx.x;                  // 64
  int c = blockIdx.y * 4 + threadIdx.y; // 192
  const float* src = bg + (size_t)c * (H_IN * W_IN);
  int l = y * 64 + x;
  #pragma unroll
  for (int ki = 0; ki < 4; ++ki)
    #pragma unroll
    for (int kj = 0; kj < 4; ++kj) {
      int yy = 2 * y + ki - 1, xx = 2 * x + kj - 1;
      float v = (yy >= 0 && yy < H_IN && xx >= 0 && xx < W_IN) ? src[yy * W_IN + xx] : 0.0f;
      BgT[((size_t)((ki * 4 + kj) * C_CH + c)) * L_P + l] = f2bf(v);
    }
}

// ======================= 256x256 8-phase GEMM (T2+T3+T4+T5) =================
// C^T[n][m] = sum_k A[m*K+k]*B[n*K+k], bf16 in, f32 out, written transposed.
// 8 waves (2M x 4N), per-wave 128x64 out. BK=64, double-buffered 128 KiB LDS.
// R3: register-reuse phases — each fragment ds_read ONCE per K-tile (24 b128
// per wave per tile, was 48): ph0 reads A-lo+B-lo -> (mlo,nlo); ph1 reads
// B-hi -> (mlo,nhi); ph2 reads A-hi (overwrites A regs) -> (mhi,nhi);
// ph3 reads nothing -> (mhi,nlo). Counted vmcnt: ph0-tail 6, ph3-tail 8
// (issue order: ph0 stages A-hi(t+1), ph1 B-hi(t+1), ph2 A-lo(t+2),
// ph3 B-lo(t+2); 2 loads each). Every staged slot's last reader is >=2
// barriers upstream (WAR-safe).

#define STAGE_A(BUF, HALF, TT) do {                                            \
  const int rbA0 = ((wave >> 2) * 128) + ((wave & 3) * 8) + (HALF) * 64;       \
  gload_lds16(A + (size_t)(tileM + rbA0      + srow8) * K + (size_t)(TT) * 64 + schunk, \
              SA[BUF] + (rbA0)      * 64);                                     \
  gload_lds16(A + (size_t)(tileM + rbA0 + 32 + srow8) * K + (size_t)(TT) * 64 + schunk, \
              SA[BUF] + (rbA0 + 32) * 64);                                     \
} while (0)

#define STAGE_B(BUF, HALF, TT) do {                                            \
  const int rbB0 = ((wave >> 2) * 64) + ((wave & 3) * 8) + (HALF) * 32;        \
  gload_lds16(B + (size_t)(tileN + rbB0       + srow8) * K + (size_t)(TT) * 64 + schunk, \
              SB[BUF] + (rbB0)       * 64);                                    \
  gload_lds16(B + (size_t)(tileN + rbB0 + 128 + srow8) * K + (size_t)(TT) * 64 + schunk, \
              SB[BUF] + (rbB0 + 128) * 64);                                    \
} while (0)

#define READ_A(MH) do {                                                        \
  _Pragma("unroll")                                                            \
  for (int m2 = 0; m2 < 4; ++m2) {                                             \
    const int r = (wave >> 2) * 128 + (MH) * 64 + m2 * 16 + fr;                \
    _Pragma("unroll")                                                          \
    for (int ks = 0; ks < 2; ++ks)                                             \
      a_[m2][ks] = *(const bf16x8*)(SAc + r * 64 + ((ks * 32 + fk) ^ xr));     \
  }                                                                            \
} while (0)

#define READ_B(DEST, NH) do {                                                  \
  _Pragma("unroll")                                                            \
  for (int n2 = 0; n2 < 2; ++n2) {                                             \
    const int r = (wave & 3) * 64 + (NH) * 32 + n2 * 16 + fr;                  \
    _Pragma("unroll")                                                          \
    for (int ks = 0; ks < 2; ++ks)                                             \
      DEST[n2][ks] = *(const bf16x8*)(SBc + r * 64 + ((ks * 32 + fk) ^ xr));   \
  }                                                                            \
} while (0)

#define MFMA_Q(MH, NH, BV) do {                                                \
  __builtin_amdgcn_s_setprio(1);                                               \
  _Pragma("unroll")                                                            \
  for (int m2 = 0; m2 < 4; ++m2)                                               \
    _Pragma("unroll")                                                          \
    for (int n2 = 0; n2 < 2; ++n2)                                             \
      _Pragma("unroll")                                                        \
      for (int ks = 0; ks < 2; ++ks)                                           \
        acc[(MH)*4 + m2][(NH)*2 + n2] = __builtin_amdgcn_mfma_f32_16x16x32_bf16( \
            a_[m2][ks], BV[n2][ks], acc[(MH)*4 + m2][(NH)*2 + n2], 0, 0, 0);   \
  __builtin_amdgcn_s_setprio(0);                                               \
} while (0)

__global__ __launch_bounds__(512, 2) void k_gemm256(const uint16_t* __restrict__ A,
                                                    const uint16_t* __restrict__ B,
                                                    float* __restrict__ Cmat,
                                                    int M, int N, int K) {
  __shared__ alignas(16) uint16_t SA[2][256 * 64];
  __shared__ alignas(16) uint16_t SB[2][256 * 64];
  const int tid = threadIdx.x;
  const int wave = tid >> 6, lane = tid & 63;
  const int tileM = blockIdx.y * 256, tileN = blockIdx.x * 256;
  const int srow8 = lane >> 3;
  const int schunk = ((lane & 7) ^ srow8) * 8;   // source-side T2 swizzle
  const int fr = lane & 15, fk = (lane >> 4) * 8;
  const int xr = (fr & 7) << 3;                  // read-side T2 swizzle (elems)
  const int NT = K >> 6;
  (void)N;

  f32x4 acc[8][4] = {};

  // prologue: [Alo0, Blo0, Ahi0, Bhi0, Alo1, Blo1] then counted wait
  STAGE_A(0, 0, 0);
  STAGE_B(0, 0, 0);
  STAGE_A(0, 1, 0);
  STAGE_B(0, 1, 0);
  if (NT > 1) {
    STAGE_A(1, 0, 1);
    STAGE_B(1, 0, 1);
    asm volatile("s_waitcnt vmcnt(8)" ::: "memory");
  } else {
    asm volatile("s_waitcnt vmcnt(4)" ::: "memory");
  }
  BARRIER();

  for (int t = 0; t < NT; ++t) {
    const int cur = t & 1, nxt = cur ^ 1;
    const uint16_t* SAc = SA[cur];
    const uint16_t* SBc = SB[cur];
    bf16x8 a_[4][2], bl_[2][2], bh_[2][2];

    // ---- ph0: (mlo,nlo); stage A-hi(t+1)
    READ_A(0);
    READ_B(bl_, 0);
    if (t + 1 < NT) STAGE_A(nxt, 1, t + 1);
    BARRIER();
    MFMA_Q(0, 0, bl_);
    if (t == NT - 1) asm volatile("s_waitcnt vmcnt(0)" ::: "memory");
    else             asm volatile("s_waitcnt vmcnt(6)" ::: "memory");
    BARRIER();

    // ---- ph1: (mlo,nhi); stage B-hi(t+1)
    READ_B(bh_, 1);
    if (t + 1 < NT) STAGE_B(nxt, 1, t + 1);
    BARRIER();
    MFMA_Q(0, 1, bh_);
    BARRIER();

    // ---- ph2: (mhi,nhi); stage A-lo(t+2); A regs overwritten with A-hi
    READ_A(1);
    if (t + 2 < NT) STAGE_A(cur, 0, t + 2);
    BARRIER();
    MFMA_Q(1, 1, bh_);
    BARRIER();

    // ---- ph3: (mhi,nlo) from held regs; stage B-lo(t+2)
    if (t + 2 < NT) STAGE_B(cur, 0, t + 2);
    BARRIER();
    MFMA_Q(1, 0, bl_);
    if (t <= NT - 3)      asm volatile("s_waitcnt vmcnt(8)" ::: "memory");
    else if (t == NT - 2) asm volatile("s_waitcnt vmcnt(4)" ::: "memory");
    BARRIER();
  }

  // epilogue: C^T write, float4 per fragment row-group
  const int r0 = (lane >> 4) * 4;
  #pragma unroll
  for (int ai = 0; ai < 8; ++ai) {
    const int m = tileM + (wave >> 2) * 128 + (ai >> 2) * 64 + (ai & 3) * 16 + r0;
    #pragma unroll
    for (int bi = 0; bi < 4; ++bi) {
      const int n = tileN + (wave & 3) * 64 + (bi >> 1) * 32 + (bi & 1) * 16 + fr;
      *(f32x4*)(Cmat + (size_t)n * M + m) = acc[ai][bi];
    }
  }
}

// ---------------- row softmax: attn[p][l] = clip(softmax_l(S[p][l]*scale[l]),1e-8)
__global__ __launch_bounds__(256) void k_softmax(const float* __restrict__ S,
                                                 const float* __restrict__ scale,
                                                 uint16_t* __restrict__ attn) {
  int p = blockIdx.x, t = threadIdx.x;
  const float4* row = (const float4*)(S + (size_t)p * L_P);
  const float4* sc4 = (const float4*)scale;
  float v[16];
  float mx = -3.4e38f;
  #pragma unroll
  for (int i = 0; i < 4; ++i) {
    float4 g = row[i * 256 + t];
    float4 s = sc4[i * 256 + t];
    v[i * 4 + 0] = g.x * s.x;
    v[i * 4 + 1] = g.y * s.y;
    v[i * 4 + 2] = g.z * s.z;
    v[i * 4 + 3] = g.w * s.w;
    mx = fmaxf(mx, fmaxf(fmaxf(v[i * 4], v[i * 4 + 1]), fmaxf(v[i * 4 + 2], v[i * 4 + 3])));
  }
  __shared__ float red[8];
  for (int off = 32; off; off >>= 1) mx = fmaxf(mx, __shfl_xor(mx, off));
  if ((t & 63) == 0) red[t >> 6] = mx;
  __syncthreads();
  mx = fmaxf(fmaxf(red[0], red[1]), fmaxf(red[2], red[3]));
  float sum = 0.0f;
  #pragma unroll
  for (int i = 0; i < 16; ++i) {
    v[i] = __expf(v[i] - mx);
    sum += v[i];
  }
  for (int off = 32; off; off >>= 1) sum += __shfl_xor(sum, off);
  if ((t & 63) == 0) red[4 + (t >> 6)] = sum;
  __syncthreads();
  sum = red[4] + red[5] + red[6] + red[7];
  float inv = 1.0f / sum;
  uint2* orow = (uint2*)(attn + (size_t)p * L_P);
  #pragma unroll
  for (int i = 0; i < 4; ++i) {
    uint32_t b0 = f2bf(fmaxf(v[i * 4 + 0] * inv, 1e-8f));
    uint32_t b1 = f2bf(fmaxf(v[i * 4 + 1] * inv, 1e-8f));
    uint32_t b2 = f2bf(fmaxf(v[i * 4 + 2] * inv, 1e-8f));
    uint32_t b3 = f2bf(fmaxf(v[i * 4 + 3] * inv, 1e-8f));
    uint2 o;
    o.x = b0 | (b1 << 16);
    o.y = b2 | (b3 << 16);
    orow[i * 256 + t] = o;
  }
}

// ---------------- gather O2T[(ki*4+kj)*192+c][p] -> out[c][Y][X], /4 --------
__global__ __launch_bounds__(256) void k_gather(const float* __restrict__ O2T,
                                                float* __restrict__ out) {
  int t = blockIdx.x * 256 + threadIdx.x;   // over 192*128*128
  int X = t & 127, Y = (t >> 7) & 127, c = t >> 14;
  int ty = Y >> 1, tx = X >> 1;
  int ya, kia, yb, kib, xa, kja, xb, kjb;
  if (Y & 1) { ya = ty;     kia = 2; yb = ty + 1; kib = 0; }
  else       { ya = ty - 1; kia = 3; yb = ty;     kib = 1; }
  if (X & 1) { xa = tx;     kja = 2; xb = tx + 1; kjb = 0; }
  else       { xa = tx - 1; kja = 3; xb = tx;     kjb = 1; }
  bool yav = (ya >= 0 && ya < 64), ybv = (yb >= 0 && yb < 64);
  bool xav = (xa >= 0 && xa < 64), xbv = (xb >= 0 && xb < 64);
  float s = 0.0f;
  if (yav && xav) s += O2T[((size_t)((kia * 4 + kja) * C_CH + c)) * L_P + ya * 64 + xa];
  if (yav && xbv) s += O2T[((size_t)((kia * 4 + kjb) * C_CH + c)) * L_P + ya * 64 + xb];
  if (ybv && xav) s += O2T[((size_t)((kib * 4 + kja) * C_CH + c)) * L_P + yb * 64 + xa];
  if (ybv && xbv) s += O2T[((size_t)((kib * 4 + kjb) * C_CH + c)) * L_P + yb * 64 + xb];
  out[t] = 0.25f * s;
}

extern "C" void kernel_launch(void* const* d_in, const int* in_sizes, int n_in,
                              void* d_out, int out_size, void* d_ws, size_t ws_size,
                              hipStream_t stream) {
  const float* bg = (const float*)d_in[0];
  const float* fg = (const float*)d_in[1];
  float* out = (float*)d_out;
  char* ws = (char*)d_ws;

  // workspace layout (bytes)
  float*    fgds  = (float*)(ws + 0);            // 4*192*64*64*4  = 12,582,912
  uint16_t* PT    = (uint16_t*)(ws + 12582912);  // 4096*1728*2    = 14,155,776
  float*    scale = (float*)(ws + 26738688);     // 4096*4         = 16,384
  uint16_t* BgT   = (uint16_t*)(ws + 26755072);  // 3072*4096*2    = 25,165,824
  float*    Sbuf  = (float*)(ws + 51920896);     // 4096*4096*4    = 67,108,864 (also O2T)
  uint16_t* attn  = (uint16_t*)(ws + 119029760); // 4096*4096*2    = 33,554,432
  (void)ws_size; (void)in_sizes; (void)n_in; (void)out_size;

  k_downsample<<<12288, 256, 0, stream>>>(fg, fgds);

  for (int b = 0; b < 4; ++b) {
    const float* bg_b = bg + (size_t)b * C_CH * H_IN * W_IN;
    const float* fg_b = fgds + (size_t)b * C_CH * H_DS * W_DS;
    float* out_b = out + (size_t)b * C_CH * H_IN * W_IN;

    k_pbuild<<<dim3(64, 48), dim3(64, 4), 0, stream>>>(fg_b, PT);
    k_scale<<<4096, 192, 0, stream>>>(fg_b, scale);
    k_bgbuild<<<dim3(64, 48), dim3(64, 4), 0, stream>>>(bg_b, BgT);

    // GEMM1: S^T == S (Gram, symmetric), M=N=4096, K=1728
    k_gemm256<<<dim3(16, 16), 512, 0, stream>>>(PT, PT, Sbuf, 4096, 4096, 1728);

    k_softmax<<<4096, 256, 0, stream>>>(Sbuf, scale, attn);

    // GEMM2: O2T[n][p] = sum_l attn[p][l]*BgT[n][l], M=4096, N=3072, K=4096
    k_gemm256<<<dim3(12, 16), 512, 0, stream>>>(attn, BgT, Sbuf, 4096, 3072, 4096);

    k_gather<<<12288, 256, 0, stream>>>(Sbuf, out_b);
  }
}